// Round 1
// 730.773 us; speedup vs baseline: 1.6731x; 1.6731x over previous
//
#include <hip/hip_runtime.h>
#include <math.h>

#define EMBED 768
#define NH 12
#define HD 64
#define HWTOK 2304
#define SCALE 0.125f

typedef unsigned short ushort_t;
typedef __attribute__((ext_vector_type(8))) short short8v;   // 8 bf16 = 4 VGPR (MFMA A/B frag)
typedef __attribute__((ext_vector_type(4))) short short4v;   // 4 bf16 = 8B
typedef __attribute__((ext_vector_type(4))) float f32x4;     // MFMA C/D frag

__device__ __forceinline__ unsigned short f2bf(float f) {    // RNE float->bf16
  unsigned u = __float_as_uint(f);
  u += 0x7fffu + ((u >> 16) & 1u);
  return (unsigned short)(u >> 16);
}
__device__ __forceinline__ float bf2f(unsigned short h) {
  return __uint_as_float(((unsigned)h) << 16);
}

// ---------------- GEMM: Y = A(MxK) * W(N,K)^T + bias ----------------
// OUT_MODE 0: fp32 Y[t*N + o]                       (final proj)
// OUT_MODE 1: bf16 hi/lo planes, head-split layout  (q/k/v)
template<int OUT_MODE>
__global__ __launch_bounds__(256)
void gemm_kernel(const float* __restrict__ A, const float* __restrict__ Wt,
                 const float* __restrict__ bias, float* __restrict__ Y,
                 ushort_t* __restrict__ Yh, ushort_t* __restrict__ Yl,
                 int M, int N, int K) {
  __shared__ float As[16][68];  // As[kk][m]  (k-major)
  __shared__ float Bs[16][68];  // Bs[kk][o]

  const int tid = threadIdx.x;
  const int m0 = blockIdx.y * 64;
  const int n0 = blockIdx.x * 64;
  const int rb = (tid >> 4) * 4;
  const int cb = (tid & 15) * 4;

  float acc[4][4] = {};

  for (int k0 = 0; k0 < K; k0 += 16) {
    __syncthreads();
    {
      int m  = tid >> 2;
      int kg = (tid & 3) * 4;
      float4 a = *(const float4*)&A [(size_t)(m0 + m) * K + k0 + kg];
      As[kg + 0][m] = a.x; As[kg + 1][m] = a.y;
      As[kg + 2][m] = a.z; As[kg + 3][m] = a.w;
      float4 b = *(const float4*)&Wt[(size_t)(n0 + m) * K + k0 + kg];
      Bs[kg + 0][m] = b.x; Bs[kg + 1][m] = b.y;
      Bs[kg + 2][m] = b.z; Bs[kg + 3][m] = b.w;
    }
    __syncthreads();
#pragma unroll
    for (int kk = 0; kk < 16; ++kk) {
      float4 a = *(const float4*)&As[kk][rb];
      float4 b = *(const float4*)&Bs[kk][cb];
      acc[0][0] += a.x * b.x; acc[0][1] += a.x * b.y; acc[0][2] += a.x * b.z; acc[0][3] += a.x * b.w;
      acc[1][0] += a.y * b.x; acc[1][1] += a.y * b.y; acc[1][2] += a.y * b.z; acc[1][3] += a.y * b.w;
      acc[2][0] += a.z * b.x; acc[2][1] += a.z * b.y; acc[2][2] += a.z * b.z; acc[2][3] += a.z * b.w;
      acc[3][0] += a.w * b.x; acc[3][1] += a.w * b.y; acc[3][2] += a.w * b.z; acc[3][3] += a.w * b.w;
    }
  }

#pragma unroll
  for (int i = 0; i < 4; ++i) {
    int t = m0 + rb + i;
    if (OUT_MODE == 0) {
#pragma unroll
      for (int j = 0; j < 4; ++j) {
        int o = n0 + cb + j;
        Y[(size_t)t * N + o] = acc[i][j] + bias[o];
      }
    } else {
      unsigned short hh[4], ll[4];
#pragma unroll
      for (int j = 0; j < 4; ++j) {
        float v = acc[i][j] + bias[n0 + cb + j];
        hh[j] = f2bf(v);
        ll[j] = f2bf(v - bf2f(hh[j]));
      }
      size_t base = ((size_t)(n0 >> 6) * M + t) * HD + cb;  // [head][t][d]
      *(short4v*)&Yh[base] = (short4v){(short)hh[0],(short)hh[1],(short)hh[2],(short)hh[3]};
      *(short4v*)&Yl[base] = (short4v){(short)ll[0],(short)ll[1],(short)ll[2],(short)ll[3]};
    }
  }
}

// ---------------- Fused attention v3: MFMA (bf16 x3 fp32-emulation) -------
// Block = (head, 64 q rows), 4 waves; wave w owns q-strip [16w,16w+16).
// Swapped product C' = K*Q^T (t rows, q cols): Q frags stay in registers all
// k-loop; P tile lands 4-consecutive-t per lane -> float4 attn stores and
// 8B packed Ps writes (per-wave buffer, no barrier). PV as out^T = V^T*P^T
// with V staged transposed in LDS. All 128B-row tiles XOR-swizzled
// (byte ^= (row&7)<<4) -> bank-floor ds_read_b128.
__global__ __launch_bounds__(256, 2)
void attn_kernel(const ushort_t* __restrict__ Qh, const ushort_t* __restrict__ Ql,
                 const ushort_t* __restrict__ Kh, const ushort_t* __restrict__ Kl,
                 const ushort_t* __restrict__ Vh, const ushort_t* __restrict__ Vl,
                 const float* __restrict__ RPH, const float* __restrict__ RPW,
                 float* __restrict__ attn, float* __restrict__ headout,
                 float* __restrict__ rowsumG) {
  const int h   = blockIdx.y;
  const int q0  = blockIdx.x * 64;
  const int tid = threadIdx.x;
  const int w = tid >> 6, lane = tid & 63, u = lane >> 4, c = lane & 15;

  __shared__ __align__(16) char smem[73728];                 // 72 KB
  ushort_t* Ksh = (ushort_t*)(smem);                          // [64 t][64 d] swz
  ushort_t* Ksl = (ushort_t*)(smem + 8192);
  ushort_t* Vsh = (ushort_t*)(smem + 16384);                  // [64 d][64 t] swz (transposed)
  ushort_t* Vsl = (ushort_t*)(smem + 24576);
  float*   relhT = (float*)(smem + 32768);                    // [48 ky][64 q]
  float*   relwT = (float*)(smem + 45056);                    // [48 kx][64 q]
  char*    PsB   = smem + 57344;                              // [4 wave][2 plane][16 q][64 t] bf16
  float*   Qstage= (float*)(smem + 57344);                    // alias (prologue only)

  const size_t hb = (size_t)h * HWTOK * HD;

  // ---- prologue: Qstage = qh+ql (fp32, exact to 2^-18) ----
  {
    int r = tid >> 2, dg = (tid & 3) * 16;
    size_t gi = hb + (size_t)(q0 + r) * HD + dg;
    short8v a0 = *(const short8v*)&Qh[gi];
    short8v a1 = *(const short8v*)&Qh[gi + 8];
    short8v b0 = *(const short8v*)&Ql[gi];
    short8v b1 = *(const short8v*)&Ql[gi + 8];
    float* dst = &Qstage[r * 64 + dg];
#pragma unroll
    for (int m = 0; m < 8; ++m) {
      dst[m]     = bf2f((unsigned short)a0[m]) + bf2f((unsigned short)b0[m]);
      dst[m + 8] = bf2f((unsigned short)a1[m]) + bf2f((unsigned short)b1[m]);
    }
  }
  __syncthreads();

  // ---- rel-pos bias tables, stored TRANSPOSED [k][q] for broadcast reads ----
  for (int idx = tid; idx < 64 * 48; idx += 256) {
    int r  = idx / 48;            // lanes share r -> Qstage reads broadcast
    int kk = idx - r * 48;
    int t  = q0 + r;
    int y  = t / 48;
    int x  = t - y * 48;
    const float4* qp = (const float4*)&Qstage[r * 64];
    const float4* rp = (const float4*)&RPH[(size_t)(y - kk + 47) * HD];
    const float4* wp = (const float4*)&RPW[(size_t)(x - kk + 47) * HD];
    float sh = 0.f, sw = 0.f;
#pragma unroll
    for (int dd = 0; dd < 16; ++dd) {
      float4 a = qp[dd], b = rp[dd], cc = wp[dd];
      sh += a.x*b.x + a.y*b.y + a.z*b.z + a.w*b.w;
      sw += a.x*cc.x + a.y*cc.y + a.z*cc.z + a.w*cc.w;
    }
    relhT[kk * 64 + r] = sh;
    relwT[kk * 64 + r] = sw;
  }
  __syncthreads();   // Qstage dead from here; PsB may be written

  // ---- Q fragments (registers for whole k-loop), straight from global ----
  short8v qf[2][2];  // [Kstep d 0/32][hi/lo]
  {
    int qrow = q0 + 16 * w + c;
    size_t base = hb + (size_t)qrow * HD + u * 8;
    qf[0][0] = *(const short8v*)&Qh[base];
    qf[1][0] = *(const short8v*)&Qh[base + 32];
    qf[0][1] = *(const short8v*)&Ql[base];
    qf[1][1] = *(const short8v*)&Ql[base + 32];
  }

  f32x4 acc_o[4];
#pragma unroll
  for (int i = 0; i < 4; ++i) acc_o[i] = (f32x4){0.f, 0.f, 0.f, 0.f};
  float rsum = 0.f;

  const int qlocal = 16 * w + c;
  float* attn_row = &attn[((size_t)h * HWTOK + q0 + qlocal) * HWTOK];
  const int swz = (c & 7) << 4;

  for (int kt0 = 0; kt0 < HWTOK; kt0 += 64) {
    __syncthreads();
    // ---- stage K tile (row-major, swizzled) ----
    {
      int r = tid >> 2, dg = (tid & 3) * 16;
      size_t gi = hb + (size_t)(kt0 + r) * HD + dg;
      short8v k0 = *(const short8v*)&Kh[gi];
      short8v k1 = *(const short8v*)&Kh[gi + 8];
      short8v k2 = *(const short8v*)&Kl[gi];
      short8v k3 = *(const short8v*)&Kl[gi + 8];
      int rs = (r & 7) << 4;
      char* kr = (char*)Ksh + r * 128;
      *(short8v*)(kr + ((dg * 2) ^ rs))      = k0;
      *(short8v*)(kr + ((dg * 2 + 16) ^ rs)) = k1;
      kr = (char*)Ksl + r * 128;
      *(short8v*)(kr + ((dg * 2) ^ rs))      = k2;
      *(short8v*)(kr + ((dg * 2 + 16) ^ rs)) = k3;
    }
    // ---- stage V tile TRANSPOSED [d][t] (4x4 micro-transpose in regs) ----
    {
      int tb4 = ((tid >> 4) & 15) * 4;   // 4 t rows
      int d4  = (tid & 15) * 4;          // 4 d cols
      short4v rh[4], rl[4];
#pragma unroll
      for (int k2 = 0; k2 < 4; ++k2) {
        size_t gi = hb + (size_t)(kt0 + tb4 + k2) * HD + d4;
        rh[k2] = *(const short4v*)&Vh[gi];
        rl[k2] = *(const short4v*)&Vl[gi];
      }
#pragma unroll
      for (int i2 = 0; i2 < 4; ++i2) {
        int d = d4 + i2;
        int off = (tb4 * 2) ^ ((d & 7) << 4);
        *(short4v*)((char*)Vsh + d * 128 + off) =
            (short4v){rh[0][i2], rh[1][i2], rh[2][i2], rh[3][i2]};
        *(short4v*)((char*)Vsl + d * 128 + off) =
            (short4v){rl[0][i2], rl[1][i2], rl[2][i2], rl[3][i2]};
      }
    }
    __syncthreads();

    // ---- QK^T (C' = K*Q^T), bias+exp, attn store, P pack ----
#pragma unroll
    for (int s = 0; s < 4; ++s) {
      const char* krh = (const char*)Ksh + (16 * s + c) * 128;
      const char* krl = (const char*)Ksl + (16 * s + c) * 128;
      short8v ah0 = *(const short8v*)(krh + ((u * 16) ^ swz));
      short8v ah1 = *(const short8v*)(krh + ((64 + u * 16) ^ swz));
      short8v al0 = *(const short8v*)(krl + ((u * 16) ^ swz));
      short8v al1 = *(const short8v*)(krl + ((64 + u * 16) ^ swz));
      f32x4 acc = (f32x4){0.f, 0.f, 0.f, 0.f};
      acc = __builtin_amdgcn_mfma_f32_16x16x32_bf16(ah0, qf[0][0], acc, 0, 0, 0);
      acc = __builtin_amdgcn_mfma_f32_16x16x32_bf16(ah1, qf[1][0], acc, 0, 0, 0);
      acc = __builtin_amdgcn_mfma_f32_16x16x32_bf16(ah0, qf[0][1], acc, 0, 0, 0);
      acc = __builtin_amdgcn_mfma_f32_16x16x32_bf16(ah1, qf[1][1], acc, 0, 0, 0);
      acc = __builtin_amdgcn_mfma_f32_16x16x32_bf16(al0, qf[0][0], acc, 0, 0, 0);
      acc = __builtin_amdgcn_mfma_f32_16x16x32_bf16(al1, qf[1][0], acc, 0, 0, 0);

      int tb = kt0 + 16 * s + 4 * u;    // C' row = 4u+reg, col = qlocal
      float pr[4];
      unsigned short hi4[4], lo4[4];
#pragma unroll
      for (int r2 = 0; r2 < 4; ++r2) {
        int t  = tb + r2;
        int ky = t / 48;
        int kx = t - ky * 48;
        float sv = acc[r2] * SCALE + relhT[ky * 64 + qlocal] + relwT[kx * 64 + qlocal];
        float e = __expf(sv);
        pr[r2] = e;
        rsum += e;
        hi4[r2] = f2bf(e);
        lo4[r2] = f2bf(e - bf2f(hi4[r2]));
      }
      *(float4*)&attn_row[tb] = make_float4(pr[0], pr[1], pr[2], pr[3]);

      char* pb = PsB + w * 4096 + c * 128;           // per-wave P buffer, row q=c
      int off = (32 * s + 8 * u) ^ swz;
      *(short4v*)(pb + off) =
          (short4v){(short)hi4[0], (short)hi4[1], (short)hi4[2], (short)hi4[3]};
      *(short4v*)(pb + 2048 + off) =
          (short4v){(short)lo4[0], (short)lo4[1], (short)lo4[2], (short)lo4[3]};
    }

    // ---- PV: out^T = V^T * P^T (same-wave Ps, compiler inserts lgkmcnt) ----
    short8v pf00, pf01, pf10, pf11;
    {
      char* pb = PsB + w * 4096 + c * 128;
      pf00 = *(const short8v*)(pb + ((u * 16) ^ swz));          // t 0..31, hi
      pf10 = *(const short8v*)(pb + ((64 + u * 16) ^ swz));     // t 32..63, hi
      pf01 = *(const short8v*)(pb + 2048 + ((u * 16) ^ swz));   // lo
      pf11 = *(const short8v*)(pb + 2048 + ((64 + u * 16) ^ swz));
    }
#pragma unroll
    for (int sd = 0; sd < 4; ++sd) {
      const char* vrh = (const char*)Vsh + (16 * sd + c) * 128;
      const char* vrl = (const char*)Vsl + (16 * sd + c) * 128;
      short8v vh0 = *(const short8v*)(vrh + ((u * 16) ^ swz));
      short8v vh1 = *(const short8v*)(vrh + ((64 + u * 16) ^ swz));
      short8v vl0 = *(const short8v*)(vrl + ((u * 16) ^ swz));
      short8v vl1 = *(const short8v*)(vrl + ((64 + u * 16) ^ swz));
      f32x4 ao = acc_o[sd];
      ao = __builtin_amdgcn_mfma_f32_16x16x32_bf16(vh0, pf00, ao, 0, 0, 0);
      ao = __builtin_amdgcn_mfma_f32_16x16x32_bf16(vh1, pf10, ao, 0, 0, 0);
      ao = __builtin_amdgcn_mfma_f32_16x16x32_bf16(vh0, pf01, ao, 0, 0, 0);
      ao = __builtin_amdgcn_mfma_f32_16x16x32_bf16(vh1, pf11, ao, 0, 0, 0);
      ao = __builtin_amdgcn_mfma_f32_16x16x32_bf16(vl0, pf00, ao, 0, 0, 0);
      ao = __builtin_amdgcn_mfma_f32_16x16x32_bf16(vl1, pf10, ao, 0, 0, 0);
      acc_o[sd] = ao;
    }
  }

  // ---- rowsum reduce across u-groups (lanes sharing c) ----
  float tot = rsum;
  tot += __shfl_xor(tot, 16, 64);
  tot += __shfl_xor(tot, 32, 64);
  if (u == 0)
    rowsumG[(size_t)h * HWTOK + q0 + qlocal] = tot;

  // ---- normalized head output: lane holds d = 16sd+4u+reg, q = qlocal ----
  float inv = 1.f / tot;
  int qrow = q0 + qlocal;
#pragma unroll
  for (int sd = 0; sd < 4; ++sd) {
    float4 o = make_float4(acc_o[sd][0] * inv, acc_o[sd][1] * inv,
                           acc_o[sd][2] * inv, acc_o[sd][3] * inv);
    *(float4*)&headout[(size_t)qrow * EMBED + h * HD + 16 * sd + 4 * u] = o;
  }
}

// ---------------- streaming normalize: attn[row][:] *= 1/rowsum[row] -------
__global__ __launch_bounds__(256)
void norm_kernel(float* __restrict__ attn, const float* __restrict__ rowsum) {
  const int row = blockIdx.x;
  const float inv = 1.f / rowsum[row];
  float4* p = (float4*)&attn[(size_t)row * HWTOK];
  for (int c = threadIdx.x; c < HWTOK / 4; c += 256) {
    float4 v = p[c];
    v.x *= inv; v.y *= inv; v.z *= inv; v.w *= inv;
    p[c] = v;
  }
}

extern "C" void kernel_launch(void* const* d_in, const int* in_sizes, int n_in,
                              void* d_out, int out_size, void* d_ws, size_t ws_size,
                              hipStream_t stream) {
  const float* hs    = (const float*)d_in[0];
  const float* wq    = (const float*)d_in[1];
  const float* bq    = (const float*)d_in[2];
  const float* wk    = (const float*)d_in[3];
  const float* bk    = (const float*)d_in[4];
  const float* wv    = (const float*)d_in[5];
  const float* bv    = (const float*)d_in[6];
  const float* wproj = (const float*)d_in[7];
  const float* bproj = (const float*)d_in[8];
  const float* rph   = (const float*)d_in[9];
  const float* rpw   = (const float*)d_in[10];

  float* out  = (float*)d_out;                    // 2304*768
  float* attn = out + (size_t)HWTOK * EMBED;      // 12*2304*2304

  const size_t QSZ = (size_t)NH * HWTOK * HD;     // 1,769,472 elems
  float* hout = (float*)d_ws;                     // HWTOK*EMBED fp32
  float* rsum = hout + (size_t)HWTOK * EMBED;     // NH*HWTOK fp32
  ushort_t* qh = (ushort_t*)(rsum + (size_t)NH * HWTOK);
  ushort_t* ql = qh + QSZ;
  ushort_t* kh = ql + QSZ;
  ushort_t* kl = kh + QSZ;
  ushort_t* vh = kl + QSZ;
  ushort_t* vl = vh + QSZ;                        // total 28,422,144 B (== old usage)

  dim3 gg(EMBED / 64, HWTOK / 64);
  gemm_kernel<1><<<gg, 256, 0, stream>>>(hs, wq, bq, nullptr, qh, ql, HWTOK, EMBED, EMBED);
  gemm_kernel<1><<<gg, 256, 0, stream>>>(hs, wk, bk, nullptr, kh, kl, HWTOK, EMBED, EMBED);
  gemm_kernel<1><<<gg, 256, 0, stream>>>(hs, wv, bv, nullptr, vh, vl, HWTOK, EMBED, EMBED);

  attn_kernel<<<dim3(HWTOK / 64, NH), 256, 0, stream>>>(qh, ql, kh, kl, vh, vl,
                                                        rph, rpw, attn, hout, rsum);

  norm_kernel<<<NH * HWTOK, 256, 0, stream>>>(attn, rsum);

  gemm_kernel<0><<<gg, 256, 0, stream>>>(hout, wproj, bproj, out, nullptr, nullptr,
                                         HWTOK, EMBED, EMBED);
}

// Round 3
// 565.273 us; speedup vs baseline: 2.1630x; 1.2928x over previous
//
#include <hip/hip_runtime.h>
#include <math.h>

#define EMBED 768
#define NH 12
#define HD 64
#define HWTOK 2304
#define SCALE 0.125f

typedef unsigned short ushort_t;
typedef __attribute__((ext_vector_type(8))) short short8v;   // 8 bf16 = 4 VGPR (MFMA A/B frag)
typedef __attribute__((ext_vector_type(4))) short short4v;   // 4 bf16 = 8B
typedef __attribute__((ext_vector_type(4))) float f32x4;     // MFMA C/D frag

__device__ __forceinline__ unsigned short f2bf(float f) {    // RNE float->bf16
  unsigned u = __float_as_uint(f);
  u += 0x7fffu + ((u >> 16) & 1u);
  return (unsigned short)(u >> 16);
}
__device__ __forceinline__ float bf2f(unsigned short h) {
  return __uint_as_float(((unsigned)h) << 16);
}

// split pair (a,b) -> packed hi word + packed lo word.
// hi = RNE bf16 of value; lo = trunc bf16 of (value - hi). |err| ~ 2^-17 rel.
__device__ __forceinline__ void split2(float a, float b, unsigned& hi, unsigned& lo) {
  unsigned ua = __float_as_uint(a), ub = __float_as_uint(b);
  unsigned ra = ua + 0x7fffu + ((ua >> 16) & 1u);
  unsigned rb = ub + 0x7fffu + ((ub >> 16) & 1u);
  float ha = __uint_as_float(ra & 0xffff0000u);
  float hb = __uint_as_float(rb & 0xffff0000u);
  hi = (ra >> 16) | (rb & 0xffff0000u);
  unsigned la = __float_as_uint(a - ha);
  unsigned lb = __float_as_uint(b - hb);
  lo = (la >> 16) | (lb & 0xffff0000u);
}

// ---------------- split: fp32 -> bf16 hi/lo planes --------------------------
__global__ __launch_bounds__(256)
void split_kernel(const float* __restrict__ src, ushort_t* __restrict__ dh,
                  ushort_t* __restrict__ dl, int n4) {
  int i = blockIdx.x * 256 + threadIdx.x;
  int stride = gridDim.x * 256;
  for (; i < n4; i += stride) {
    float4 v = ((const float4*)src)[i];
    unsigned h0, l0, h1, l1;
    split2(v.x, v.y, h0, l0);
    split2(v.z, v.w, h1, l1);
    *(uint2*)&dh[(size_t)i * 4] = make_uint2(h0, h1);
    *(uint2*)&dl[(size_t)i * 4] = make_uint2(l0, l1);
  }
}

// load 16 fp32, split, write swizzled 16B chunks to hi/lo LDS planes
__device__ __forceinline__ void stage16(const float* __restrict__ src, char* dh, char* dl,
                                        int b0, int rs) {
  const float4* s4 = (const float4*)src;
  float4 f0 = s4[0], f1 = s4[1], f2 = s4[2], f3 = s4[3];
  uint4 H0, L0, H1, L1;
  split2(f0.x, f0.y, H0.x, L0.x); split2(f0.z, f0.w, H0.y, L0.y);
  split2(f1.x, f1.y, H0.z, L0.z); split2(f1.z, f1.w, H0.w, L0.w);
  split2(f2.x, f2.y, H1.x, L1.x); split2(f2.z, f2.w, H1.y, L1.y);
  split2(f3.x, f3.y, H1.z, L1.z); split2(f3.z, f3.w, H1.w, L1.w);
  *(uint4*)(dh + (b0 ^ rs))        = H0;
  *(uint4*)(dh + ((b0 + 16) ^ rs)) = H1;
  *(uint4*)(dl + (b0 ^ rs))        = L0;
  *(uint4*)(dl + ((b0 + 16) ^ rs)) = L1;
}

// ---------------- GEMM: Y = A(MxK) * W(N,K)^T + bias, MFMA bf16 x3 ---------
// W is fp32, split in-register during staging. A: IN_F32=0 -> pre-split bf16
// hi/lo planes (Ah/Al); IN_F32=1 -> fp32 (Af), split during staging.
// 64x64 tile, 4 waves at 32x32. LDS [64 rows][64 k] bf16 per plane,
// 16B-chunk XOR swizzle (byte ^= (row&7)<<4) -> bank-uniform ds_read_b128.
// OUT_MODE 0: fp32 Y[t*N+o];  OUT_MODE 1: bf16 hi/lo head-split planes.
template<int IN_F32, int OUT_MODE>
__global__ __launch_bounds__(256)
void gemm_bf3(const ushort_t* __restrict__ Ah, const ushort_t* __restrict__ Al,
              const float* __restrict__ Af, const float* __restrict__ W,
              const float* __restrict__ bias, float* __restrict__ Y,
              ushort_t* __restrict__ Yh, ushort_t* __restrict__ Yl,
              int M, int N, int K) {
  __shared__ __align__(16) char smem[32768];   // sAh sAl sWh sWl (8KB each); epilogue: Cs[64][68] f32

  const int tid  = threadIdx.x;
  const int w    = tid >> 6;
  const int lane = tid & 63;
  const int u    = lane >> 4;       // 0..3
  const int cc   = lane & 15;       // 0..15
  const int mw   = w >> 1, nw = w & 1;
  const int m0   = blockIdx.y * 64;
  const int n0   = blockIdx.x * 64;
  const int sr   = tid >> 2;        // staging row 0..63
  const int sq   = tid & 3;         // staging k-quarter (16 elems)
  const int srs  = (sr & 7) << 4;

  char* sAh_w = smem;
  char* sAl_w = smem + 8192;
  char* sWh_w = smem + 16384;
  char* sWl_w = smem + 24576;
  const int swzc = (cc & 7) << 4;

  f32x4 acc[2][2];
#pragma unroll
  for (int i = 0; i < 2; ++i)
#pragma unroll
    for (int j = 0; j < 2; ++j) acc[i][j] = (f32x4){0.f, 0.f, 0.f, 0.f};

  for (int k0 = 0; k0 < K; k0 += 64) {
    __syncthreads();
    // ---- stage A (row m0+sr, k quarter sq) ----
    if (IN_F32) {
      stage16(&Af[(size_t)(m0 + sr) * K + k0 + sq * 16],
              sAh_w + sr * 128, sAl_w + sr * 128, sq * 32, srs);
    } else {
      const ushort_t* ap = &Ah[(size_t)(m0 + sr) * K + k0 + sq * 16];
      const ushort_t* lp = &Al[(size_t)(m0 + sr) * K + k0 + sq * 16];
      uint4 h0 = *(const uint4*)ap;
      uint4 h1 = *(const uint4*)(ap + 8);
      uint4 l0 = *(const uint4*)lp;
      uint4 l1 = *(const uint4*)(lp + 8);
      *(uint4*)(sAh_w + sr * 128 + ((sq * 32) ^ srs))      = h0;
      *(uint4*)(sAh_w + sr * 128 + ((sq * 32 + 16) ^ srs)) = h1;
      *(uint4*)(sAl_w + sr * 128 + ((sq * 32) ^ srs))      = l0;
      *(uint4*)(sAl_w + sr * 128 + ((sq * 32 + 16) ^ srs)) = l1;
    }
    // ---- stage W (row n0+sr, fp32 -> split) ----
    stage16(&W[(size_t)(n0 + sr) * K + k0 + sq * 16],
            sWh_w + sr * 128, sWl_w + sr * 128, sq * 32, srs);
    __syncthreads();

#pragma unroll
    for (int k2 = 0; k2 < 2; ++k2) {
      const int ko = k2 * 64;
      short8v a_h[2], a_l[2], b_h[2], b_l[2];
#pragma unroll
      for (int i = 0; i < 2; ++i) {
        int off = (32 * mw + 16 * i + cc) * 128 + ((u * 16 + ko) ^ swzc);
        a_h[i] = *(const short8v*)(sAh_w + off);
        a_l[i] = *(const short8v*)(sAl_w + off);
      }
#pragma unroll
      for (int j = 0; j < 2; ++j) {
        int off = (32 * nw + 16 * j + cc) * 128 + ((u * 16 + ko) ^ swzc);
        b_h[j] = *(const short8v*)(sWh_w + off);
        b_l[j] = *(const short8v*)(sWl_w + off);
      }
#pragma unroll
      for (int i = 0; i < 2; ++i)
#pragma unroll
        for (int j = 0; j < 2; ++j) {
          acc[i][j] = __builtin_amdgcn_mfma_f32_16x16x32_bf16(a_h[i], b_h[j], acc[i][j], 0, 0, 0);
          acc[i][j] = __builtin_amdgcn_mfma_f32_16x16x32_bf16(a_h[i], b_l[j], acc[i][j], 0, 0, 0);
          acc[i][j] = __builtin_amdgcn_mfma_f32_16x16x32_bf16(a_l[i], b_h[j], acc[i][j], 0, 0, 0);
        }
    }
  }

  // ---- epilogue: stage C through LDS for coalesced stores ----
  __syncthreads();
  float* Cs = (float*)smem;      // [64][68]
#pragma unroll
  for (int i = 0; i < 2; ++i)
#pragma unroll
    for (int j = 0; j < 2; ++j)
#pragma unroll
      for (int r = 0; r < 4; ++r)
        Cs[(32 * mw + 16 * i + 4 * u + r) * 68 + 32 * nw + 16 * j + cc] = acc[i][j][r];
  __syncthreads();

  {
    int rr = tid >> 2, cg = (tid & 3) * 16;
    float v[16];
#pragma unroll
    for (int e = 0; e < 4; ++e) {
      float4 cv = *(const float4*)&Cs[rr * 68 + cg + 4 * e];
      float4 bv = *(const float4*)&bias[n0 + cg + 4 * e];
      v[4 * e + 0] = cv.x + bv.x; v[4 * e + 1] = cv.y + bv.y;
      v[4 * e + 2] = cv.z + bv.z; v[4 * e + 3] = cv.w + bv.w;
    }
    if (OUT_MODE == 0) {
#pragma unroll
      for (int e = 0; e < 4; ++e)
        *(float4*)&Y[(size_t)(m0 + rr) * N + n0 + cg + 4 * e] =
            make_float4(v[4 * e], v[4 * e + 1], v[4 * e + 2], v[4 * e + 3]);
    } else {
      unsigned short hh[16], ll[16];
#pragma unroll
      for (int e = 0; e < 16; ++e) {
        hh[e] = f2bf(v[e]);
        ll[e] = f2bf(v[e] - bf2f(hh[e]));
      }
      size_t base = ((size_t)(n0 >> 6) * M + (m0 + rr)) * HD + cg;
      *(short8v*)&Yh[base]     = (short8v){(short)hh[0],(short)hh[1],(short)hh[2],(short)hh[3],
                                           (short)hh[4],(short)hh[5],(short)hh[6],(short)hh[7]};
      *(short8v*)&Yh[base + 8] = (short8v){(short)hh[8],(short)hh[9],(short)hh[10],(short)hh[11],
                                           (short)hh[12],(short)hh[13],(short)hh[14],(short)hh[15]};
      *(short8v*)&Yl[base]     = (short8v){(short)ll[0],(short)ll[1],(short)ll[2],(short)ll[3],
                                           (short)ll[4],(short)ll[5],(short)ll[6],(short)ll[7]};
      *(short8v*)&Yl[base + 8] = (short8v){(short)ll[8],(short)ll[9],(short)ll[10],(short)ll[11],
                                           (short)ll[12],(short)ll[13],(short)ll[14],(short)ll[15]};
    }
  }
}

// ---------------- Fused attention v4: two-pass, normalized writes ---------
// Pass 1: QK^T -> exp -> rsum + P(hi/lo) -> PV  (no attn store).
// Pass 2: re-run QK^T, store exp(s)/rsum directly -> norm kernel deleted.
// V staging remap spreads transposed LDS writes over all 16 byte-slots
// (8-way -> 4-way = throughput floor for 8B stores). XCD-swizzled flat
// block id (432 = 8*54) clusters same-head blocks per XCD L2.
__global__ __launch_bounds__(256, 2)
void attn_kernel(const ushort_t* __restrict__ Qh, const ushort_t* __restrict__ Ql,
                 const ushort_t* __restrict__ Kh, const ushort_t* __restrict__ Kl,
                 const ushort_t* __restrict__ Vh, const ushort_t* __restrict__ Vl,
                 const float* __restrict__ RPH, const float* __restrict__ RPW,
                 float* __restrict__ attn, float* __restrict__ headout) {
  const int f   = blockIdx.y * gridDim.x + blockIdx.x;       // dispatch-flat
  const int lgl = (f & 7) * 54 + (f >> 3);                   // XCD-contiguous
  const int h   = lgl / 36;
  const int q0  = (lgl - h * 36) * 64;
  const int tid = threadIdx.x;
  const int w = tid >> 6, lane = tid & 63, u = lane >> 4, c = lane & 15;

  __shared__ __align__(16) char smem[73728];                 // 72 KB
  ushort_t* Ksh = (ushort_t*)(smem);                          // [64 t][64 d] swz
  ushort_t* Ksl = (ushort_t*)(smem + 8192);
  ushort_t* Vsh = (ushort_t*)(smem + 16384);                  // [64 d][64 t] swz (transposed)
  ushort_t* Vsl = (ushort_t*)(smem + 24576);
  float*   relhT = (float*)(smem + 32768);                    // [48 ky][64 q]
  float*   relwT = (float*)(smem + 45056);                    // [48 kx][64 q]
  char*    PsB   = smem + 57344;                              // [4 wave][2 plane][16 q][64 t] bf16
  float*   Qstage= (float*)(smem + 57344);                    // alias (prologue only)

  const size_t hb = (size_t)h * HWTOK * HD;

  // ---- prologue: Qstage = qh+ql (fp32, exact to ~2^-17) ----
  {
    int r = tid >> 2, dg = (tid & 3) * 16;
    size_t gi = hb + (size_t)(q0 + r) * HD + dg;
    short8v a0 = *(const short8v*)&Qh[gi];
    short8v a1 = *(const short8v*)&Qh[gi + 8];
    short8v b0 = *(const short8v*)&Ql[gi];
    short8v b1 = *(const short8v*)&Ql[gi + 8];
    float* dst = &Qstage[r * 64 + dg];
#pragma unroll
    for (int m = 0; m < 8; ++m) {
      dst[m]     = bf2f((unsigned short)a0[m]) + bf2f((unsigned short)b0[m]);
      dst[m + 8] = bf2f((unsigned short)a1[m]) + bf2f((unsigned short)b1[m]);
    }
  }
  __syncthreads();

  // ---- rel-pos bias tables, stored TRANSPOSED [k][q] ----
  for (int idx = tid; idx < 64 * 48; idx += 256) {
    int r  = idx / 48;
    int kk = idx - r * 48;
    int t  = q0 + r;
    int y  = t / 48;
    int x  = t - y * 48;
    const float4* qp = (const float4*)&Qstage[r * 64];
    const float4* rp = (const float4*)&RPH[(size_t)(y - kk + 47) * HD];
    const float4* wp = (const float4*)&RPW[(size_t)(x - kk + 47) * HD];
    float sh = 0.f, sw = 0.f;
#pragma unroll
    for (int dd = 0; dd < 16; ++dd) {
      float4 a = qp[dd], b = rp[dd], cc2 = wp[dd];
      sh += a.x*b.x + a.y*b.y + a.z*b.z + a.w*b.w;
      sw += a.x*cc2.x + a.y*cc2.y + a.z*cc2.z + a.w*cc2.w;
    }
    relhT[kk * 64 + r] = sh;
    relwT[kk * 64 + r] = sw;
  }
  __syncthreads();   // Qstage dead; PsB may be written

  // ---- Q fragments in registers for both passes ----
  short8v qf[2][2];  // [k-chunk d0/d32][hi/lo]
  {
    int qrow = q0 + 16 * w + c;
    size_t base = hb + (size_t)qrow * HD + u * 8;
    qf[0][0] = *(const short8v*)&Qh[base];
    qf[1][0] = *(const short8v*)&Qh[base + 32];
    qf[0][1] = *(const short8v*)&Ql[base];
    qf[1][1] = *(const short8v*)&Ql[base + 32];
  }

  f32x4 acc_o[4];
#pragma unroll
  for (int i = 0; i < 4; ++i) acc_o[i] = (f32x4){0.f, 0.f, 0.f, 0.f};
  float rsum = 0.f;

  const int qlocal = 16 * w + c;
  float* attn_row = &attn[((size_t)h * HWTOK + q0 + qlocal) * HWTOK];
  const int swz = (c & 7) << 4;

  // ================= PASS 1: rsum + PV =================
  for (int kt0 = 0; kt0 < HWTOK; kt0 += 64) {
    __syncthreads();
    // ---- stage K tile (row-major, swizzled) ----
    {
      int r = tid >> 2, dg = (tid & 3) * 16;
      size_t gi = hb + (size_t)(kt0 + r) * HD + dg;
      short8v k0 = *(const short8v*)&Kh[gi];
      short8v k1 = *(const short8v*)&Kh[gi + 8];
      short8v k2 = *(const short8v*)&Kl[gi];
      short8v k3 = *(const short8v*)&Kl[gi + 8];
      int rs = (r & 7) << 4;
      char* kr = (char*)Ksh + r * 128;
      *(short8v*)(kr + ((dg * 2) ^ rs))      = k0;
      *(short8v*)(kr + ((dg * 2 + 16) ^ rs)) = k1;
      kr = (char*)Ksl + r * 128;
      *(short8v*)(kr + ((dg * 2) ^ rs))      = k2;
      *(short8v*)(kr + ((dg * 2 + 16) ^ rs)) = k3;
    }
    // ---- stage V tile TRANSPOSED [d][t]; conflict-spread mapping ----
    {
      int t4 = ((tid >> 2) & 15) * 4;                 // 4 t rows
      int d4 = ((tid & 3) + (tid >> 6) * 4) * 4;      // 4 d cols
      short4v rh[4], rl[4];
#pragma unroll
      for (int k2 = 0; k2 < 4; ++k2) {
        size_t gi = hb + (size_t)(kt0 + t4 + k2) * HD + d4;
        rh[k2] = *(const short4v*)&Vh[gi];
        rl[k2] = *(const short4v*)&Vl[gi];
      }
#pragma unroll
      for (int i2 = 0; i2 < 4; ++i2) {
        int d = d4 + i2;
        int off = (t4 * 2) ^ ((d & 7) << 4);
        *(short4v*)((char*)Vsh + d * 128 + off) =
            (short4v){rh[0][i2], rh[1][i2], rh[2][i2], rh[3][i2]};
        *(short4v*)((char*)Vsl + d * 128 + off) =
            (short4v){rl[0][i2], rl[1][i2], rl[2][i2], rl[3][i2]};
      }
    }
    __syncthreads();

    // ---- QK^T (C' = K*Q^T), bias+exp, rsum, P pack ----
#pragma unroll
    for (int s = 0; s < 4; ++s) {
      const char* krh = (const char*)Ksh + (16 * s + c) * 128;
      const char* krl = (const char*)Ksl + (16 * s + c) * 128;
      short8v ah0 = *(const short8v*)(krh + ((u * 16) ^ swz));
      short8v ah1 = *(const short8v*)(krh + ((64 + u * 16) ^ swz));
      short8v al0 = *(const short8v*)(krl + ((u * 16) ^ swz));
      short8v al1 = *(const short8v*)(krl + ((64 + u * 16) ^ swz));
      f32x4 acc = (f32x4){0.f, 0.f, 0.f, 0.f};
      acc = __builtin_amdgcn_mfma_f32_16x16x32_bf16(ah0, qf[0][0], acc, 0, 0, 0);
      acc = __builtin_amdgcn_mfma_f32_16x16x32_bf16(ah1, qf[1][0], acc, 0, 0, 0);
      acc = __builtin_amdgcn_mfma_f32_16x16x32_bf16(ah0, qf[0][1], acc, 0, 0, 0);
      acc = __builtin_amdgcn_mfma_f32_16x16x32_bf16(ah1, qf[1][1], acc, 0, 0, 0);
      acc = __builtin_amdgcn_mfma_f32_16x16x32_bf16(al0, qf[0][0], acc, 0, 0, 0);
      acc = __builtin_amdgcn_mfma_f32_16x16x32_bf16(al1, qf[1][0], acc, 0, 0, 0);

      int tb = kt0 + 16 * s + 4 * u;
      unsigned short hi4[4], lo4[4];
#pragma unroll
      for (int r2 = 0; r2 < 4; ++r2) {
        int t  = tb + r2;
        int ky = t / 48;
        int kx = t - ky * 48;
        float sv = acc[r2] * SCALE + relhT[ky * 64 + qlocal] + relwT[kx * 64 + qlocal];
        float e = __expf(sv);
        rsum += e;
        hi4[r2] = f2bf(e);
        lo4[r2] = f2bf(e - bf2f(hi4[r2]));
      }
      char* pb = PsB + w * 4096 + c * 128;
      int off = (32 * s + 8 * u) ^ swz;
      *(short4v*)(pb + off) =
          (short4v){(short)hi4[0], (short)hi4[1], (short)hi4[2], (short)hi4[3]};
      *(short4v*)(pb + 2048 + off) =
          (short4v){(short)lo4[0], (short)lo4[1], (short)lo4[2], (short)lo4[3]};
    }

    // ---- PV: out^T = V^T * P^T (same-wave Ps; compiler inserts lgkmcnt) ----
    short8v pf00, pf01, pf10, pf11;
    {
      char* pb = PsB + w * 4096 + c * 128;
      pf00 = *(const short8v*)(pb + ((u * 16) ^ swz));
      pf10 = *(const short8v*)(pb + ((64 + u * 16) ^ swz));
      pf01 = *(const short8v*)(pb + 2048 + ((u * 16) ^ swz));
      pf11 = *(const short8v*)(pb + 2048 + ((64 + u * 16) ^ swz));
    }
#pragma unroll
    for (int sd = 0; sd < 4; ++sd) {
      const char* vrh = (const char*)Vsh + (16 * sd + c) * 128;
      const char* vrl = (const char*)Vsl + (16 * sd + c) * 128;
      short8v vh0 = *(const short8v*)(vrh + ((u * 16) ^ swz));
      short8v vh1 = *(const short8v*)(vrh + ((64 + u * 16) ^ swz));
      short8v vl0 = *(const short8v*)(vrl + ((u * 16) ^ swz));
      short8v vl1 = *(const short8v*)(vrl + ((64 + u * 16) ^ swz));
      f32x4 ao = acc_o[sd];
      ao = __builtin_amdgcn_mfma_f32_16x16x32_bf16(vh0, pf00, ao, 0, 0, 0);
      ao = __builtin_amdgcn_mfma_f32_16x16x32_bf16(vh1, pf10, ao, 0, 0, 0);
      ao = __builtin_amdgcn_mfma_f32_16x16x32_bf16(vh0, pf01, ao, 0, 0, 0);
      ao = __builtin_amdgcn_mfma_f32_16x16x32_bf16(vh1, pf11, ao, 0, 0, 0);
      ao = __builtin_amdgcn_mfma_f32_16x16x32_bf16(vl0, pf00, ao, 0, 0, 0);
      ao = __builtin_amdgcn_mfma_f32_16x16x32_bf16(vl1, pf10, ao, 0, 0, 0);
      acc_o[sd] = ao;
    }
  }

  // ---- rowsum reduce across u-groups ----
  float tot = rsum;
  tot += __shfl_xor(tot, 16, 64);
  tot += __shfl_xor(tot, 32, 64);
  const float inv = 1.f / tot;

  // ---- normalized head output (fp32; proj GEMM splits on the fly) ----
  {
    int qrow = q0 + qlocal;
#pragma unroll
    for (int sd = 0; sd < 4; ++sd) {
      float4 o = make_float4(acc_o[sd][0] * inv, acc_o[sd][1] * inv,
                             acc_o[sd][2] * inv, acc_o[sd][3] * inv);
      *(float4*)&headout[(size_t)qrow * EMBED + h * HD + 16 * sd + 4 * u] = o;
    }
  }

  // ================= PASS 2: recompute scores, store normalized ==========
  for (int kt0 = 0; kt0 < HWTOK; kt0 += 64) {
    __syncthreads();
    {
      int r = tid >> 2, dg = (tid & 3) * 16;
      size_t gi = hb + (size_t)(kt0 + r) * HD + dg;
      short8v k0 = *(const short8v*)&Kh[gi];
      short8v k1 = *(const short8v*)&Kh[gi + 8];
      short8v k2 = *(const short8v*)&Kl[gi];
      short8v k3 = *(const short8v*)&Kl[gi + 8];
      int rs = (r & 7) << 4;
      char* kr = (char*)Ksh + r * 128;
      *(short8v*)(kr + ((dg * 2) ^ rs))      = k0;
      *(short8v*)(kr + ((dg * 2 + 16) ^ rs)) = k1;
      kr = (char*)Ksl + r * 128;
      *(short8v*)(kr + ((dg * 2) ^ rs))      = k2;
      *(short8v*)(kr + ((dg * 2 + 16) ^ rs)) = k3;
    }
    __syncthreads();

#pragma unroll
    for (int s = 0; s < 4; ++s) {
      const char* krh = (const char*)Ksh + (16 * s + c) * 128;
      const char* krl = (const char*)Ksl + (16 * s + c) * 128;
      short8v ah0 = *(const short8v*)(krh + ((u * 16) ^ swz));
      short8v ah1 = *(const short8v*)(krh + ((64 + u * 16) ^ swz));
      short8v al0 = *(const short8v*)(krl + ((u * 16) ^ swz));
      short8v al1 = *(const short8v*)(krl + ((64 + u * 16) ^ swz));
      f32x4 acc = (f32x4){0.f, 0.f, 0.f, 0.f};
      acc = __builtin_amdgcn_mfma_f32_16x16x32_bf16(ah0, qf[0][0], acc, 0, 0, 0);
      acc = __builtin_amdgcn_mfma_f32_16x16x32_bf16(ah1, qf[1][0], acc, 0, 0, 0);
      acc = __builtin_amdgcn_mfma_f32_16x16x32_bf16(ah0, qf[0][1], acc, 0, 0, 0);
      acc = __builtin_amdgcn_mfma_f32_16x16x32_bf16(ah1, qf[1][1], acc, 0, 0, 0);
      acc = __builtin_amdgcn_mfma_f32_16x16x32_bf16(al0, qf[0][0], acc, 0, 0, 0);
      acc = __builtin_amdgcn_mfma_f32_16x16x32_bf16(al1, qf[1][0], acc, 0, 0, 0);

      int tb = kt0 + 16 * s + 4 * u;
      float pr[4];
#pragma unroll
      for (int r2 = 0; r2 < 4; ++r2) {
        int t  = tb + r2;
        int ky = t / 48;
        int kx = t - ky * 48;
        float sv = acc[r2] * SCALE + relhT[ky * 64 + qlocal] + relwT[kx * 64 + qlocal];
        pr[r2] = __expf(sv) * inv;
      }
      *(float4*)&attn_row[tb] = make_float4(pr[0], pr[1], pr[2], pr[3]);
    }
  }
}

extern "C" void kernel_launch(void* const* d_in, const int* in_sizes, int n_in,
                              void* d_out, int out_size, void* d_ws, size_t ws_size,
                              hipStream_t stream) {
  const float* hs    = (const float*)d_in[0];
  const float* wq    = (const float*)d_in[1];
  const float* bq    = (const float*)d_in[2];
  const float* wk    = (const float*)d_in[3];
  const float* bk    = (const float*)d_in[4];
  const float* wv    = (const float*)d_in[5];
  const float* bv    = (const float*)d_in[6];
  const float* wproj = (const float*)d_in[7];
  const float* bproj = (const float*)d_in[8];
  const float* rph   = (const float*)d_in[9];
  const float* rpw   = (const float*)d_in[10];

  float* out  = (float*)d_out;                    // 2304*768
  float* attn = out + (size_t)HWTOK * EMBED;      // 12*2304*2304

  const size_t QSZ = (size_t)NH * HWTOK * HD;     // 1,769,472 elems

  // workspace: 28,311,552 B total (<= proven 28.4 MB budget), ALL in d_ws.
  // region0 (QSZ floats): ah/al (hs bf16 planes) during projections, then
  // hout (fp32 head output) from attn onward -- stream-ordered reuse.
  char* wsb = (char*)d_ws;
  float*    hout = (float*)wsb;
  ushort_t* ah   = (ushort_t*)wsb;
  ushort_t* al   = ah + QSZ;
  ushort_t* qh   = (ushort_t*)(wsb + QSZ * 4);
  ushort_t* ql   = qh + QSZ;
  ushort_t* kh   = ql + QSZ;
  ushort_t* kl   = kh + QSZ;
  ushort_t* vh   = kl + QSZ;
  ushort_t* vl   = vh + QSZ;

  const int HS4 = (int)((size_t)HWTOK * EMBED / 4);  // 442,368

  split_kernel<<<1728, 256, 0, stream>>>(hs, ah, al, HS4);

  dim3 gg(EMBED / 64, HWTOK / 64);
  gemm_bf3<0, 1><<<gg, 256, 0, stream>>>(ah, al, nullptr, wq, bq, nullptr, qh, ql,
                                         HWTOK, EMBED, EMBED);
  gemm_bf3<0, 1><<<gg, 256, 0, stream>>>(ah, al, nullptr, wk, bk, nullptr, kh, kl,
                                         HWTOK, EMBED, EMBED);
  gemm_bf3<0, 1><<<gg, 256, 0, stream>>>(ah, al, nullptr, wv, bv, nullptr, vh, vl,
                                         HWTOK, EMBED, EMBED);

  attn_kernel<<<dim3(HWTOK / 64, NH), 256, 0, stream>>>(qh, ql, kh, kl, vh, vl,
                                                        rph, rpw, attn, hout);

  gemm_bf3<1, 0><<<gg, 256, 0, stream>>>(nullptr, nullptr, hout, wproj, bproj, out,
                                         nullptr, nullptr, HWTOK, EMBED, EMBED);
}

// Round 4
// 522.029 us; speedup vs baseline: 2.3421x; 1.0828x over previous
//
#include <hip/hip_runtime.h>
#include <math.h>

#define EMBED 768
#define NH 12
#define HD 64
#define HWTOK 2304
#define SCALE 0.125f

typedef unsigned short ushort_t;
typedef __attribute__((ext_vector_type(8))) short short8v;   // 8 bf16 = 4 VGPR (MFMA A/B frag)
typedef __attribute__((ext_vector_type(4))) short short4v;   // 4 bf16 = 8B
typedef __attribute__((ext_vector_type(4))) float f32x4;     // MFMA C/D frag

__device__ __forceinline__ unsigned short f2bf(float f) {    // RNE float->bf16
  unsigned u = __float_as_uint(f);
  u += 0x7fffu + ((u >> 16) & 1u);
  return (unsigned short)(u >> 16);
}
__device__ __forceinline__ float bf2f(unsigned short h) {
  return __uint_as_float(((unsigned)h) << 16);
}

// split pair (a,b) -> packed hi word + packed lo word.
// hi = RNE bf16 of value; lo = trunc bf16 of (value - hi). |err| ~ 2^-17 rel.
__device__ __forceinline__ void split2(float a, float b, unsigned& hi, unsigned& lo) {
  unsigned ua = __float_as_uint(a), ub = __float_as_uint(b);
  unsigned ra = ua + 0x7fffu + ((ua >> 16) & 1u);
  unsigned rb = ub + 0x7fffu + ((ub >> 16) & 1u);
  float ha = __uint_as_float(ra & 0xffff0000u);
  float hb = __uint_as_float(rb & 0xffff0000u);
  hi = (ra >> 16) | (rb & 0xffff0000u);
  unsigned la = __float_as_uint(a - ha);
  unsigned lb = __float_as_uint(b - hb);
  lo = (la >> 16) | (lb & 0xffff0000u);
}

// ---------------- split: fp32 -> bf16 hi/lo planes --------------------------
__global__ __launch_bounds__(256)
void split_kernel(const float* __restrict__ src, ushort_t* __restrict__ dh,
                  ushort_t* __restrict__ dl, int n4) {
  int i = blockIdx.x * 256 + threadIdx.x;
  int stride = gridDim.x * 256;
  for (; i < n4; i += stride) {
    float4 v = ((const float4*)src)[i];
    unsigned h0, l0, h1, l1;
    split2(v.x, v.y, h0, l0);
    split2(v.z, v.w, h1, l1);
    *(uint2*)&dh[(size_t)i * 4] = make_uint2(h0, h1);
    *(uint2*)&dl[(size_t)i * 4] = make_uint2(l0, l1);
  }
}

// ---------------- GEMM: Y = A(MxK) * W(N,K)^T + bias, MFMA bf16 x3 ---------
// FUSED=1: one dispatch does q,k,v (which = b/432); grid 1296, XCD-chunked.
// Async staging (T14): tile t+1's global loads are issued after the second
// barrier so their latency hides under tile t's MFMA; the vmcnt wait lands
// at the next iteration's ds_write.
// W fp32, split in-register during staging. A: IN_F32=0 -> pre-split planes;
// IN_F32=1 -> fp32, split during staging.
// LDS [64 rows][64 k] bf16 per plane, byte ^= (row&7)<<4 swizzle.
template<int IN_F32, int OUT_MODE, int FUSED>
__global__ __launch_bounds__(256, 3)
void gemm_bf3(const ushort_t* __restrict__ Ah, const ushort_t* __restrict__ Al,
              const float* __restrict__ Af,
              const float* __restrict__ W0, const float* __restrict__ W1,
              const float* __restrict__ W2,
              const float* __restrict__ b0, const float* __restrict__ b1,
              const float* __restrict__ b2,
              float* __restrict__ Y, ushort_t* __restrict__ Yh0,
              int M, int N, int K) {
  __shared__ __align__(16) char smem[32768];   // sAh sAl sWh sWl (8KB each); epilogue: Cs[64][68]

  const int tid  = threadIdx.x;
  const int g    = blockIdx.x;
  int which, r;
  if (FUSED) { int b = (g & 7) * 162 + (g >> 3); which = b / 432; r = b - which * 432; }
  else       { int b = (g & 7) * 54  + (g >> 3); which = 0;       r = b; }
  const float* W    = FUSED ? (which == 0 ? W0 : which == 1 ? W1 : W2) : W0;
  const float* bias = FUSED ? (which == 0 ? b0 : which == 1 ? b1 : b2) : b0;
  const int n0 = (r % 12) * 64;
  const int m0 = (r / 12) * 64;

  const int w    = tid >> 6;
  const int lane = tid & 63;
  const int u    = lane >> 4;
  const int cc   = lane & 15;
  const int mw   = w >> 1, nw = w & 1;
  const int sr   = tid >> 2;        // staging row 0..63
  const int sq   = tid & 3;         // k-quarter (16 elems)
  const int srs  = (sr & 7) << 4;

  char* sAh_ = smem;
  char* sAl_ = smem + 8192;
  char* sWh_ = smem + 16384;
  char* sWl_ = smem + 24576;
  const int swzc = (cc & 7) << 4;

  // prefetch registers
  uint4  pah0, pah1, pal0, pal1;             // A planes
  float4 paf0, paf1, paf2, paf3;             // A fp32
  float4 pw0, pw1, pw2, pw3;                 // W fp32

  auto loadA = [&](int k0) {
    if (IN_F32) {
      const float4* s4 = (const float4*)&Af[(size_t)(m0 + sr) * K + k0 + sq * 16];
      paf0 = s4[0]; paf1 = s4[1]; paf2 = s4[2]; paf3 = s4[3];
    } else {
      const ushort_t* ap = &Ah[(size_t)(m0 + sr) * K + k0 + sq * 16];
      const ushort_t* lp = &Al[(size_t)(m0 + sr) * K + k0 + sq * 16];
      pah0 = *(const uint4*)ap; pah1 = *(const uint4*)(ap + 8);
      pal0 = *(const uint4*)lp; pal1 = *(const uint4*)(lp + 8);
    }
  };
  auto loadW = [&](int k0) {
    const float4* s4 = (const float4*)&W[(size_t)(n0 + sr) * K + k0 + sq * 16];
    pw0 = s4[0]; pw1 = s4[1]; pw2 = s4[2]; pw3 = s4[3];
  };
  auto storeStage = [&]() {
    char* ar = sAh_ + sr * 128;
    char* lr = sAl_ + sr * 128;
    if (IN_F32) {
      uint4 H0, L0, H1, L1;
      split2(paf0.x, paf0.y, H0.x, L0.x); split2(paf0.z, paf0.w, H0.y, L0.y);
      split2(paf1.x, paf1.y, H0.z, L0.z); split2(paf1.z, paf1.w, H0.w, L0.w);
      split2(paf2.x, paf2.y, H1.x, L1.x); split2(paf2.z, paf2.w, H1.y, L1.y);
      split2(paf3.x, paf3.y, H1.z, L1.z); split2(paf3.z, paf3.w, H1.w, L1.w);
      *(uint4*)(ar + ((sq * 32) ^ srs))      = H0;
      *(uint4*)(ar + ((sq * 32 + 16) ^ srs)) = H1;
      *(uint4*)(lr + ((sq * 32) ^ srs))      = L0;
      *(uint4*)(lr + ((sq * 32 + 16) ^ srs)) = L1;
    } else {
      *(uint4*)(ar + ((sq * 32) ^ srs))      = pah0;
      *(uint4*)(ar + ((sq * 32 + 16) ^ srs)) = pah1;
      *(uint4*)(lr + ((sq * 32) ^ srs))      = pal0;
      *(uint4*)(lr + ((sq * 32 + 16) ^ srs)) = pal1;
    }
    uint4 H0, L0, H1, L1;
    split2(pw0.x, pw0.y, H0.x, L0.x); split2(pw0.z, pw0.w, H0.y, L0.y);
    split2(pw1.x, pw1.y, H0.z, L0.z); split2(pw1.z, pw1.w, H0.w, L0.w);
    split2(pw2.x, pw2.y, H1.x, L1.x); split2(pw2.z, pw2.w, H1.y, L1.y);
    split2(pw3.x, pw3.y, H1.z, L1.z); split2(pw3.z, pw3.w, H1.w, L1.w);
    char* wr = sWh_ + sr * 128;
    *(uint4*)(wr + ((sq * 32) ^ srs))      = H0;
    *(uint4*)(wr + ((sq * 32 + 16) ^ srs)) = H1;
    wr = sWl_ + sr * 128;
    *(uint4*)(wr + ((sq * 32) ^ srs))      = L0;
    *(uint4*)(wr + ((sq * 32 + 16) ^ srs)) = L1;
  };

  f32x4 acc[2][2];
#pragma unroll
  for (int i = 0; i < 2; ++i)
#pragma unroll
    for (int j = 0; j < 2; ++j) acc[i][j] = (f32x4){0.f, 0.f, 0.f, 0.f};

  loadA(0); loadW(0);
  for (int k0 = 0; k0 < K; k0 += 64) {
    __syncthreads();            // prior compute done, LDS free
    storeStage();               // vmcnt wait for prefetched regs lands here
    __syncthreads();            // LDS visible
    if (k0 + 64 < K) { loadA(k0 + 64); loadW(k0 + 64); }  // in flight under MFMA

#pragma unroll
    for (int k2 = 0; k2 < 2; ++k2) {
      const int ko = k2 * 64;
      short8v a_h[2], a_l[2], b_h[2], b_l[2];
#pragma unroll
      for (int i = 0; i < 2; ++i) {
        int off = (32 * mw + 16 * i + cc) * 128 + ((u * 16 + ko) ^ swzc);
        a_h[i] = *(const short8v*)(sAh_ + off);
        a_l[i] = *(const short8v*)(sAl_ + off);
      }
#pragma unroll
      for (int j = 0; j < 2; ++j) {
        int off = (32 * nw + 16 * j + cc) * 128 + ((u * 16 + ko) ^ swzc);
        b_h[j] = *(const short8v*)(sWh_ + off);
        b_l[j] = *(const short8v*)(sWl_ + off);
      }
#pragma unroll
      for (int i = 0; i < 2; ++i)
#pragma unroll
        for (int j = 0; j < 2; ++j) {
          acc[i][j] = __builtin_amdgcn_mfma_f32_16x16x32_bf16(a_h[i], b_h[j], acc[i][j], 0, 0, 0);
          acc[i][j] = __builtin_amdgcn_mfma_f32_16x16x32_bf16(a_h[i], b_l[j], acc[i][j], 0, 0, 0);
          acc[i][j] = __builtin_amdgcn_mfma_f32_16x16x32_bf16(a_l[i], b_h[j], acc[i][j], 0, 0, 0);
        }
    }
  }

  // ---- epilogue: stage C through LDS for coalesced stores ----
  __syncthreads();
  float* Cs = (float*)smem;      // [64][68]
#pragma unroll
  for (int i = 0; i < 2; ++i)
#pragma unroll
    for (int j = 0; j < 2; ++j)
#pragma unroll
      for (int rr2 = 0; rr2 < 4; ++rr2)
        Cs[(32 * mw + 16 * i + 4 * u + rr2) * 68 + 32 * nw + 16 * j + cc] = acc[i][j][rr2];
  __syncthreads();

  {
    int rr = tid >> 2, cg = (tid & 3) * 16;
    float v[16];
#pragma unroll
    for (int e = 0; e < 4; ++e) {
      float4 cv = *(const float4*)&Cs[rr * 68 + cg + 4 * e];
      float4 bv = *(const float4*)&bias[n0 + cg + 4 * e];
      v[4 * e + 0] = cv.x + bv.x; v[4 * e + 1] = cv.y + bv.y;
      v[4 * e + 2] = cv.z + bv.z; v[4 * e + 3] = cv.w + bv.w;
    }
    if (OUT_MODE == 0) {
#pragma unroll
      for (int e = 0; e < 4; ++e)
        *(float4*)&Y[(size_t)(m0 + rr) * N + n0 + cg + 4 * e] =
            make_float4(v[4 * e], v[4 * e + 1], v[4 * e + 2], v[4 * e + 3]);
    } else {
      const size_t MN = (size_t)M * N;
      ushort_t* Yh = Yh0 + (size_t)which * 2 * MN;
      ushort_t* Yl = Yh + MN;
      unsigned short hh[16], ll[16];
#pragma unroll
      for (int e = 0; e < 16; ++e) {
        hh[e] = f2bf(v[e]);
        ll[e] = f2bf(v[e] - bf2f(hh[e]));
      }
      size_t base = ((size_t)(n0 >> 6) * M + (m0 + rr)) * HD + cg;
      *(short8v*)&Yh[base]     = (short8v){(short)hh[0],(short)hh[1],(short)hh[2],(short)hh[3],
                                           (short)hh[4],(short)hh[5],(short)hh[6],(short)hh[7]};
      *(short8v*)&Yh[base + 8] = (short8v){(short)hh[8],(short)hh[9],(short)hh[10],(short)hh[11],
                                           (short)hh[12],(short)hh[13],(short)hh[14],(short)hh[15]};
      *(short8v*)&Yl[base]     = (short8v){(short)ll[0],(short)ll[1],(short)ll[2],(short)ll[3],
                                           (short)ll[4],(short)ll[5],(short)ll[6],(short)ll[7]};
      *(short8v*)&Yl[base + 8] = (short8v){(short)ll[8],(short)ll[9],(short)ll[10],(short)ll[11],
                                           (short)ll[12],(short)ll[13],(short)ll[14],(short)ll[15]};
    }
  }
}

// ---------------- Fused attention v5: two-pass + async staging -------------
// Pass 1: QK^T -> exp -> rsum + P(hi/lo) -> PV  (no attn store).
// Pass 2: re-run QK^T, store exp(s)/rsum directly (no norm kernel).
// T14: next tile's K/V global loads are issued after the staging barrier so
// latency hides under QK/PV; setprio(1) wraps MFMA clusters (T5, attn +).
__global__ __launch_bounds__(256, 2)
void attn_kernel(const ushort_t* __restrict__ Qh, const ushort_t* __restrict__ Ql,
                 const ushort_t* __restrict__ Kh, const ushort_t* __restrict__ Kl,
                 const ushort_t* __restrict__ Vh, const ushort_t* __restrict__ Vl,
                 const float* __restrict__ RPH, const float* __restrict__ RPW,
                 float* __restrict__ attn, float* __restrict__ headout) {
  const int f   = blockIdx.y * gridDim.x + blockIdx.x;       // dispatch-flat
  const int lgl = (f & 7) * 54 + (f >> 3);                   // XCD-contiguous
  const int h   = lgl / 36;
  const int q0  = (lgl - h * 36) * 64;
  const int tid = threadIdx.x;
  const int w = tid >> 6, lane = tid & 63, u = lane >> 4, c = lane & 15;

  __shared__ __align__(16) char smem[73728];                 // 72 KB
  ushort_t* Ksh = (ushort_t*)(smem);                          // [64 t][64 d] swz
  ushort_t* Ksl = (ushort_t*)(smem + 8192);
  ushort_t* Vsh = (ushort_t*)(smem + 16384);                  // [64 d][64 t] swz (transposed)
  ushort_t* Vsl = (ushort_t*)(smem + 24576);
  float*   relhT = (float*)(smem + 32768);                    // [48 ky][64 q]
  float*   relwT = (float*)(smem + 45056);                    // [48 kx][64 q]
  char*    PsB   = smem + 57344;                              // [4 wave][2 plane][16 q][64 t] bf16
  float*   Qstage= (float*)(smem + 57344);                    // alias (prologue only)

  const size_t hb = (size_t)h * HWTOK * HD;

  // ---- staging prefetch registers + helpers ----
  const int str = tid >> 2, sdg = (tid & 3) * 16;             // K staging coords
  const int vt4 = ((tid >> 2) & 15) * 4;                      // V staging coords
  const int vd4 = ((tid & 3) + (tid >> 6) * 4) * 4;
  short8v kA, kB, kC, kD;
  short4v vrh[4], vrl[4];

  auto loadK = [&](int kt0) {
    size_t gi = hb + (size_t)(kt0 + str) * HD + sdg;
    kA = *(const short8v*)&Kh[gi];
    kB = *(const short8v*)&Kh[gi + 8];
    kC = *(const short8v*)&Kl[gi];
    kD = *(const short8v*)&Kl[gi + 8];
  };
  auto loadV = [&](int kt0) {
#pragma unroll
    for (int k2 = 0; k2 < 4; ++k2) {
      size_t gi = hb + (size_t)(kt0 + vt4 + k2) * HD + vd4;
      vrh[k2] = *(const short4v*)&Vh[gi];
      vrl[k2] = *(const short4v*)&Vl[gi];
    }
  };
  auto writeK = [&]() {
    int rs = (str & 7) << 4;
    char* kr = (char*)Ksh + str * 128;
    *(short8v*)(kr + ((sdg * 2) ^ rs))      = kA;
    *(short8v*)(kr + ((sdg * 2 + 16) ^ rs)) = kB;
    kr = (char*)Ksl + str * 128;
    *(short8v*)(kr + ((sdg * 2) ^ rs))      = kC;
    *(short8v*)(kr + ((sdg * 2 + 16) ^ rs)) = kD;
  };
  auto writeV = [&]() {
#pragma unroll
    for (int i2 = 0; i2 < 4; ++i2) {
      int d = vd4 + i2;
      int off = (vt4 * 2) ^ ((d & 7) << 4);
      *(short4v*)((char*)Vsh + d * 128 + off) =
          (short4v){vrh[0][i2], vrh[1][i2], vrh[2][i2], vrh[3][i2]};
      *(short4v*)((char*)Vsl + d * 128 + off) =
          (short4v){vrl[0][i2], vrl[1][i2], vrl[2][i2], vrl[3][i2]};
    }
  };

  // ---- prologue: Qstage = qh+ql (fp32, exact to ~2^-17) ----
  {
    int r = tid >> 2, dg = (tid & 3) * 16;
    size_t gi = hb + (size_t)(q0 + r) * HD + dg;
    short8v a0 = *(const short8v*)&Qh[gi];
    short8v a1 = *(const short8v*)&Qh[gi + 8];
    short8v b0 = *(const short8v*)&Ql[gi];
    short8v b1 = *(const short8v*)&Ql[gi + 8];
    float* dst = &Qstage[r * 64 + dg];
#pragma unroll
    for (int m = 0; m < 8; ++m) {
      dst[m]     = bf2f((unsigned short)a0[m]) + bf2f((unsigned short)b0[m]);
      dst[m + 8] = bf2f((unsigned short)a1[m]) + bf2f((unsigned short)b1[m]);
    }
  }
  loadK(0); loadV(0);            // tile-0 prefetch hides under rel-pos compute
  __syncthreads();

  // ---- rel-pos bias tables, stored TRANSPOSED [k][q] ----
  for (int idx = tid; idx < 64 * 48; idx += 256) {
    int r  = idx / 48;
    int kk = idx - r * 48;
    int t  = q0 + r;
    int y  = t / 48;
    int x  = t - y * 48;
    const float4* qp = (const float4*)&Qstage[r * 64];
    const float4* rp = (const float4*)&RPH[(size_t)(y - kk + 47) * HD];
    const float4* wp = (const float4*)&RPW[(size_t)(x - kk + 47) * HD];
    float sh = 0.f, sw = 0.f;
#pragma unroll
    for (int dd = 0; dd < 16; ++dd) {
      float4 a = qp[dd], b = rp[dd], cc2 = wp[dd];
      sh += a.x*b.x + a.y*b.y + a.z*b.z + a.w*b.w;
      sw += a.x*cc2.x + a.y*cc2.y + a.z*cc2.z + a.w*cc2.w;
    }
    relhT[kk * 64 + r] = sh;
    relwT[kk * 64 + r] = sw;
  }
  __syncthreads();   // Qstage dead; PsB may be written

  // ---- Q fragments in registers for both passes ----
  short8v qf[2][2];  // [k-chunk d0/d32][hi/lo]
  {
    int qrow = q0 + 16 * w + c;
    size_t base = hb + (size_t)qrow * HD + u * 8;
    qf[0][0] = *(const short8v*)&Qh[base];
    qf[1][0] = *(const short8v*)&Qh[base + 32];
    qf[0][1] = *(const short8v*)&Ql[base];
    qf[1][1] = *(const short8v*)&Ql[base + 32];
  }

  f32x4 acc_o[4];
#pragma unroll
  for (int i = 0; i < 4; ++i) acc_o[i] = (f32x4){0.f, 0.f, 0.f, 0.f};
  float rsum = 0.f;

  const int qlocal = 16 * w + c;
  float* attn_row = &attn[((size_t)h * HWTOK + q0 + qlocal) * HWTOK];
  const int swz = (c & 7) << 4;

  // ================= PASS 1: rsum + PV =================
  for (int kt0 = 0; kt0 < HWTOK; kt0 += 64) {
    __syncthreads();            // prior tile's LDS reads done
    writeK(); writeV();         // vmcnt wait for prefetch lands here
    __syncthreads();            // LDS visible
    if (kt0 + 64 < HWTOK) { loadK(kt0 + 64); loadV(kt0 + 64); }

    // ---- QK^T (C' = K*Q^T), bias+exp, rsum, P pack ----
#pragma unroll
    for (int s = 0; s < 4; ++s) {
      const char* krh = (const char*)Ksh + (16 * s + c) * 128;
      const char* krl = (const char*)Ksl + (16 * s + c) * 128;
      short8v ah0 = *(const short8v*)(krh + ((u * 16) ^ swz));
      short8v ah1 = *(const short8v*)(krh + ((64 + u * 16) ^ swz));
      short8v al0 = *(const short8v*)(krl + ((u * 16) ^ swz));
      short8v al1 = *(const short8v*)(krl + ((64 + u * 16) ^ swz));
      f32x4 acc = (f32x4){0.f, 0.f, 0.f, 0.f};
      __builtin_amdgcn_s_setprio(1);
      acc = __builtin_amdgcn_mfma_f32_16x16x32_bf16(ah0, qf[0][0], acc, 0, 0, 0);
      acc = __builtin_amdgcn_mfma_f32_16x16x32_bf16(ah1, qf[1][0], acc, 0, 0, 0);
      acc = __builtin_amdgcn_mfma_f32_16x16x32_bf16(ah0, qf[0][1], acc, 0, 0, 0);
      acc = __builtin_amdgcn_mfma_f32_16x16x32_bf16(ah1, qf[1][1], acc, 0, 0, 0);
      acc = __builtin_amdgcn_mfma_f32_16x16x32_bf16(al0, qf[0][0], acc, 0, 0, 0);
      acc = __builtin_amdgcn_mfma_f32_16x16x32_bf16(al1, qf[1][0], acc, 0, 0, 0);
      __builtin_amdgcn_s_setprio(0);

      int tb = kt0 + 16 * s + 4 * u;
      unsigned short hi4[4], lo4[4];
#pragma unroll
      for (int r2 = 0; r2 < 4; ++r2) {
        int t  = tb + r2;
        int ky = t / 48;
        int kx = t - ky * 48;
        float sv = acc[r2] * SCALE + relhT[ky * 64 + qlocal] + relwT[kx * 64 + qlocal];
        float e = __expf(sv);
        rsum += e;
        hi4[r2] = f2bf(e);
        lo4[r2] = f2bf(e - bf2f(hi4[r2]));
      }
      char* pb = PsB + w * 4096 + c * 128;
      int off = (32 * s + 8 * u) ^ swz;
      *(short4v*)(pb + off) =
          (short4v){(short)hi4[0], (short)hi4[1], (short)hi4[2], (short)hi4[3]};
      *(short4v*)(pb + 2048 + off) =
          (short4v){(short)lo4[0], (short)lo4[1], (short)lo4[2], (short)lo4[3]};
    }

    // ---- PV: out^T = V^T * P^T (same-wave Ps; compiler inserts lgkmcnt) ----
    short8v pf00, pf01, pf10, pf11;
    {
      char* pb = PsB + w * 4096 + c * 128;
      pf00 = *(const short8v*)(pb + ((u * 16) ^ swz));
      pf10 = *(const short8v*)(pb + ((64 + u * 16) ^ swz));
      pf01 = *(const short8v*)(pb + 2048 + ((u * 16) ^ swz));
      pf11 = *(const short8v*)(pb + 2048 + ((64 + u * 16) ^ swz));
    }
#pragma unroll
    for (int sd = 0; sd < 4; ++sd) {
      const char* vrh_ = (const char*)Vsh + (16 * sd + c) * 128;
      const char* vrl_ = (const char*)Vsl + (16 * sd + c) * 128;
      short8v vh0 = *(const short8v*)(vrh_ + ((u * 16) ^ swz));
      short8v vh1 = *(const short8v*)(vrh_ + ((64 + u * 16) ^ swz));
      short8v vl0 = *(const short8v*)(vrl_ + ((u * 16) ^ swz));
      short8v vl1 = *(const short8v*)(vrl_ + ((64 + u * 16) ^ swz));
      f32x4 ao = acc_o[sd];
      __builtin_amdgcn_s_setprio(1);
      ao = __builtin_amdgcn_mfma_f32_16x16x32_bf16(vh0, pf00, ao, 0, 0, 0);
      ao = __builtin_amdgcn_mfma_f32_16x16x32_bf16(vh1, pf10, ao, 0, 0, 0);
      ao = __builtin_amdgcn_mfma_f32_16x16x32_bf16(vh0, pf01, ao, 0, 0, 0);
      ao = __builtin_amdgcn_mfma_f32_16x16x32_bf16(vh1, pf11, ao, 0, 0, 0);
      ao = __builtin_amdgcn_mfma_f32_16x16x32_bf16(vl0, pf00, ao, 0, 0, 0);
      ao = __builtin_amdgcn_mfma_f32_16x16x32_bf16(vl1, pf10, ao, 0, 0, 0);
      __builtin_amdgcn_s_setprio(0);
      acc_o[sd] = ao;
    }
  }

  // ---- rowsum reduce across u-groups ----
  float tot = rsum;
  tot += __shfl_xor(tot, 16, 64);
  tot += __shfl_xor(tot, 32, 64);
  const float inv = 1.f / tot;

  // ---- normalized head output (fp32; proj GEMM splits on the fly) ----
  {
    int qrow = q0 + qlocal;
#pragma unroll
    for (int sd = 0; sd < 4; ++sd) {
      float4 o = make_float4(acc_o[sd][0] * inv, acc_o[sd][1] * inv,
                             acc_o[sd][2] * inv, acc_o[sd][3] * inv);
      *(float4*)&headout[(size_t)qrow * EMBED + h * HD + 16 * sd + 4 * u] = o;
    }
  }

  // ================= PASS 2: recompute scores, store normalized ==========
  loadK(0);
  for (int kt0 = 0; kt0 < HWTOK; kt0 += 64) {
    __syncthreads();
    writeK();
    __syncthreads();
    if (kt0 + 64 < HWTOK) loadK(kt0 + 64);

#pragma unroll
    for (int s = 0; s < 4; ++s) {
      const char* krh = (const char*)Ksh + (16 * s + c) * 128;
      const char* krl = (const char*)Ksl + (16 * s + c) * 128;
      short8v ah0 = *(const short8v*)(krh + ((u * 16) ^ swz));
      short8v ah1 = *(const short8v*)(krh + ((64 + u * 16) ^ swz));
      short8v al0 = *(const short8v*)(krl + ((u * 16) ^ swz));
      short8v al1 = *(const short8v*)(krl + ((64 + u * 16) ^ swz));
      f32x4 acc = (f32x4){0.f, 0.f, 0.f, 0.f};
      __builtin_amdgcn_s_setprio(1);
      acc = __builtin_amdgcn_mfma_f32_16x16x32_bf16(ah0, qf[0][0], acc, 0, 0, 0);
      acc = __builtin_amdgcn_mfma_f32_16x16x32_bf16(ah1, qf[1][0], acc, 0, 0, 0);
      acc = __builtin_amdgcn_mfma_f32_16x16x32_bf16(ah0, qf[0][1], acc, 0, 0, 0);
      acc = __builtin_amdgcn_mfma_f32_16x16x32_bf16(ah1, qf[1][1], acc, 0, 0, 0);
      acc = __builtin_amdgcn_mfma_f32_16x16x32_bf16(al0, qf[0][0], acc, 0, 0, 0);
      acc = __builtin_amdgcn_mfma_f32_16x16x32_bf16(al1, qf[1][0], acc, 0, 0, 0);
      __builtin_amdgcn_s_setprio(0);

      int tb = kt0 + 16 * s + 4 * u;
      float pr[4];
#pragma unroll
      for (int r2 = 0; r2 < 4; ++r2) {
        int t  = tb + r2;
        int ky = t / 48;
        int kx = t - ky * 48;
        float sv = acc[r2] * SCALE + relhT[ky * 64 + qlocal] + relwT[kx * 64 + qlocal];
        pr[r2] = __expf(sv) * inv;
      }
      *(float4*)&attn_row[tb] = make_float4(pr[0], pr[1], pr[2], pr[3]);
    }
  }
}

extern "C" void kernel_launch(void* const* d_in, const int* in_sizes, int n_in,
                              void* d_out, int out_size, void* d_ws, size_t ws_size,
                              hipStream_t stream) {
  const float* hs    = (const float*)d_in[0];
  const float* wq    = (const float*)d_in[1];
  const float* bq    = (const float*)d_in[2];
  const float* wk    = (const float*)d_in[3];
  const float* bk    = (const float*)d_in[4];
  const float* wv    = (const float*)d_in[5];
  const float* bv    = (const float*)d_in[6];
  const float* wproj = (const float*)d_in[7];
  const float* bproj = (const float*)d_in[8];
  const float* rph   = (const float*)d_in[9];
  const float* rpw   = (const float*)d_in[10];

  float* out  = (float*)d_out;                    // 2304*768
  float* attn = out + (size_t)HWTOK * EMBED;      // 12*2304*2304

  const size_t QSZ = (size_t)NH * HWTOK * HD;     // 1,769,472 elems

  // workspace: 28,311,552 B total, ALL in d_ws.
  // region0 (QSZ floats): ah/al (hs bf16 planes) during projections, then
  // hout (fp32 head output) from attn onward -- stream-ordered reuse.
  char* wsb = (char*)d_ws;
  float*    hout = (float*)wsb;
  ushort_t* ah   = (ushort_t*)wsb;
  ushort_t* al   = ah + QSZ;
  ushort_t* qh   = (ushort_t*)(wsb + QSZ * 4);    // qh,ql,kh,kl,vh,vl contiguous

  const int HS4 = (int)((size_t)HWTOK * EMBED / 4);  // 442,368

  split_kernel<<<1728, 256, 0, stream>>>(hs, ah, al, HS4);

  // fused q/k/v projections: one dispatch, 1296 blocks (8 XCD x 162)
  gemm_bf3<0, 1, 1><<<1296, 256, 0, stream>>>(ah, al, nullptr, wq, wk, wv,
                                              bq, bk, bv, nullptr, qh,
                                              HWTOK, EMBED, EMBED);

  ushort_t* ql = qh + QSZ;
  ushort_t* kh = ql + QSZ;
  ushort_t* kl = kh + QSZ;
  ushort_t* vh = kl + QSZ;
  ushort_t* vl = vh + QSZ;
  attn_kernel<<<dim3(HWTOK / 64, NH), 256, 0, stream>>>(qh, ql, kh, kl, vh, vl,
                                                        rph, rpw, attn, hout);

  gemm_bf3<1, 0, 0><<<432, 256, 0, stream>>>(nullptr, nullptr, hout, wproj, nullptr,
                                             nullptr, bproj, nullptr, nullptr, out,
                                             nullptr, HWTOK, EMBED, EMBED);
}